// Round 13
// baseline (383.585 us; speedup 1.0000x reference)
//
#include <hip/hip_runtime.h>
#include <math.h>

#define N_B 4
#define SEQ 2048
#define DM  512
#define H_N 8
#define DH  64

typedef unsigned short ushort_t;
typedef __attribute__((ext_vector_type(8))) short short8_t;
typedef __attribute__((ext_vector_type(4))) float float4_t;

#define LOG2E 1.4426950408889634074f

__device__ __forceinline__ ushort_t f2bf(float f) {
    unsigned int x = __float_as_uint(f);
    unsigned int lsb = (x >> 16) & 1u;
    x += 0x7fffu + lsb;
    return (ushort_t)(x >> 16);
}
__device__ __forceinline__ unsigned int cvtpk_bf16(float a, float b) {
    unsigned int r;
    asm("v_cvt_pk_bf16_f32 %0, %1, %2" : "=v"(r) : "v"(a), "v"(b));
    return r;   // lo = bf16(a), hi = bf16(b), RNE
}
__device__ __forceinline__ float fexp2(float x) {
#if __has_builtin(__builtin_amdgcn_exp2f)
    return __builtin_amdgcn_exp2f(x);
#else
    return exp2f(x);
#endif
}

// Merged pre-pass: query + 4 weights -> bf16 (RNE); bias concat.
#define Q4 1048576   // query float4 groups
#define W4 65536     // per-weight float4 groups
__global__ __launch_bounds__(256)
void prep(const float* __restrict__ query,
          const float* __restrict__ Wq, const float* __restrict__ Wk,
          const float* __restrict__ Wv, const float* __restrict__ Wp,
          const float* __restrict__ bq, const float* __restrict__ bk,
          const float* __restrict__ bv, const float* __restrict__ bp,
          ushort_t* __restrict__ q16, ushort_t* __restrict__ w16,
          float* __restrict__ bcat)
{
    int i = blockIdx.x * 256 + threadIdx.x;
    if (i < Q4) {
        float4 x = ((const float4*)query)[i];
        uint2 p;
        p.x = cvtpk_bf16(x.x, x.y);
        p.y = cvtpk_bf16(x.z, x.w);
        ((uint2*)q16)[i] = p;
    } else if (i < Q4 + 4 * W4) {
        int wi = i - Q4;
        int w = wi >> 16;
        const float* W = (w == 0) ? Wq : (w == 1) ? Wk : (w == 2) ? Wv : Wp;
        float4 x = ((const float4*)W)[wi & (W4 - 1)];
        uint2 p;
        p.x = cvtpk_bf16(x.x, x.y);
        p.y = cvtpk_bf16(x.z, x.w);
        ((uint2*)w16)[wi] = p;
    } else {
        int bi = i - (Q4 + 4 * W4);
        if (bi < 512) {
            int seg = bi >> 7;
            int off = bi & 127;
            const float* B = (seg == 0) ? bq : (seg == 1) ? bk : (seg == 2) ? bv : bp;
            ((float4*)bcat)[bi] = ((const float4*)B)[off];
        }
    }
}

// Single-pass bf16 MFMA GEMM: C[m,c] = sum_k A[m,k]*W[c,k] + bias[c]
// MODE 0: B rows 0..1535 (Wq|Wk|Wv): scatter bf16 to q/k (split-head) and vt (transposed).
// MODE 1: fp32 out [m][512].
template<int MODE>
__global__ __launch_bounds__(256)
void mgemm(const ushort_t* __restrict__ A, const ushort_t* __restrict__ B,
           const float* __restrict__ bias,
           ushort_t* __restrict__ q_o, ushort_t* __restrict__ k_o,
           ushort_t* __restrict__ vt_o, float* __restrict__ p_o)
{
    __shared__ __align__(16) ushort_t As[128][40];
    __shared__ __align__(16) ushort_t Bs[128][40];

    const int t     = threadIdx.x;
    const int wid   = t >> 6;
    const int lane  = t & 63;
    const int lan16 = lane & 15;
    const int quad  = lane >> 4;
    const int wm    = (wid & 1) * 64;
    const int wn    = (wid >> 1) * 64;

    const int col0 = blockIdx.x * 128;
    const int row0 = blockIdx.y * 128;

    const int srow = t >> 1;
    const int skof = (t & 1) * 16;

    float4_t acc[4][4];
    #pragma unroll
    for (int i = 0; i < 4; i++)
        #pragma unroll
        for (int j = 0; j < 4; j++) acc[i][j] = (float4_t){0.f, 0.f, 0.f, 0.f};

    for (int k0 = 0; k0 < DM; k0 += 32) {
        const size_t aoff = (size_t)(row0 + srow) * DM + k0 + skof;
        const size_t boff = (size_t)(col0 + srow) * DM + k0 + skof;
        uint4 a0 = *(const uint4*)(A + aoff);
        uint4 a1 = *(const uint4*)(A + aoff + 8);
        uint4 b0 = *(const uint4*)(B + boff);
        uint4 b1 = *(const uint4*)(B + boff + 8);
        __syncthreads();
        *(uint4*)&As[srow][skof]     = a0;
        *(uint4*)&As[srow][skof + 8] = a1;
        *(uint4*)&Bs[srow][skof]     = b0;
        *(uint4*)&Bs[srow][skof + 8] = b1;
        __syncthreads();

        short8_t af[4], bf[4];
        #pragma unroll
        for (int i = 0; i < 4; i++) {
            af[i] = *(const short8_t*)&As[wm + i * 16 + lan16][quad * 8];
            bf[i] = *(const short8_t*)&Bs[wn + i * 16 + lan16][quad * 8];
        }
        #pragma unroll
        for (int i = 0; i < 4; i++)
            #pragma unroll
            for (int j = 0; j < 4; j++)
                acc[i][j] = __builtin_amdgcn_mfma_f32_16x16x32_bf16(af[i], bf[j], acc[i][j], 0, 0, 0);
    }

    #pragma unroll
    for (int j = 0; j < 4; j++) {
        int col = col0 + wn + j * 16 + lan16;
        float bv = bias[col];
        #pragma unroll
        for (int i = 0; i < 4; i++) {
            #pragma unroll
            for (int reg = 0; reg < 4; reg++) {
                int row = row0 + wm + i * 16 + quad * 4 + reg;
                float v = acc[i][j][reg] + bv;
                if (MODE == 0) {
                    int w = col >> 9;
                    int c = col & 511;
                    int hh = c & 7, dh = c >> 3;
                    int n = row >> 11, s = row & 2047;
                    if (w == 0)
                        q_o[(((size_t)(n * H_N + hh)) * SEQ + s) * DH + dh] = f2bf(v);
                    else if (w == 1)
                        k_o[(((size_t)(n * H_N + hh)) * SEQ + s) * DH + dh] = f2bf(v);
                    else
                        vt_o[(((size_t)(n * H_N + hh)) * DH + dh) * SEQ + s] = f2bf(v);
                } else {
                    p_o[(size_t)row * DM + col] = v;
                }
            }
        }
    }
}

// MFMA flash attention, S^T orientation, no-max softmax (scores provably bounded).
// Block = (nh, 64 q-rows); 4 waves, wave owns 16 q-rows. Grid (32, 32) = 1024 blocks.
// K and V^T fragments loaded DIRECTLY from global (L2-resident): no LDS staging and
// no barriers in the K-loop (Pp is wave-private).
// S^T = K.Q^T  (C: col=lan16=qrow, row=quad*4+reg=key)
// O^T = V^T.P^T (C: col=lan16=qrow, row=quad*4+reg=dim)
__global__ __launch_bounds__(256, 4)
void attn_k(const ushort_t* __restrict__ qw, const ushort_t* __restrict__ kw,
            const ushort_t* __restrict__ vt, const float* __restrict__ lsc,
            const float* __restrict__ rpe, ushort_t* __restrict__ ctx)
{
    __shared__ __align__(16) unsigned int Pp[4][16][36]; // [wave][qrow16][key-pair]
    __shared__ float tbl[2112];   // sigmoid(rpe)*log2e, reversed window

    const int t     = threadIdx.x;
    const int wid   = t >> 6;
    const int lane  = t & 63;
    const int lan16 = lane & 15;
    const int quad  = lane >> 4;

    const int qt = blockIdx.x;    // 0..31
    const int nh = blockIdx.y;    // n*H_N + h
    const int h  = nh & 7;
    const int q0 = qt * 64;

    const size_t headoff = (size_t)nh * SEQ * DH;
    const ushort_t* qh  = qw + headoff;
    const ushort_t* kh  = kw + headoff;
    const ushort_t* vth = vt + headoff;

    float ls = lsc[h];
    const float lm = 4.60517018598809136804f;   // log(100)
    if (ls > lm) ls = lm;
    const float scale2 = __expf(ls) * 0.04419417382415921757f * LOG2E;

    // tbl[w] = log2e*sigmoid(rpe[q0 + 2110 - w]), w in [0, 2110].
    // Lane lookup: w = 63 - local_row + key  ->  rpe[q0 + lr - key + 2047].
    for (int w = t; w < 2111; w += 256) {
        int v = q0 + 2110 - w;                 // in [q0, q0+2110] subset of [0, 4094]
        float x = rpe[v * H_N + h];
        tbl[w] = LOG2E / (1.0f + __expf(-x));
    }

    // Q as B-operand: lane lan16 = qrow (q0 + wid*16 + lan16), holds d = half*32+quad*8..+7
    short8_t qb0, qb1;
    {
        const ushort_t* src = qh + (size_t)(q0 + wid * 16 + lan16) * DH + quad * 8;
        qb0 = *(const short8_t*)(src);
        qb1 = *(const short8_t*)(src + 32);
    }
    __syncthreads();   // tbl ready; only barrier in the kernel

    float l_run = 0.f;
    float4_t o[4];
    #pragma unroll
    for (int ds = 0; ds < 4; ds++) o[ds] = (float4_t){0.f, 0.f, 0.f, 0.f};

    for (int j0 = 0; j0 < SEQ; j0 += 64) {
        // ---- S^T = K.Q^T : K A-frags direct from global (L2)
        float4_t st[4];
        #pragma unroll
        for (int sub = 0; sub < 4; sub++) {
            const ushort_t* kp = kh + (size_t)(j0 + sub * 16 + lan16) * DH + quad * 8;
            short8_t ka0 = *(const short8_t*)(kp);
            short8_t ka1 = *(const short8_t*)(kp + 32);
            float4_t a = (float4_t){0.f, 0.f, 0.f, 0.f};
            a = __builtin_amdgcn_mfma_f32_16x16x32_bf16(ka0, qb0, a, 0, 0, 0);
            a = __builtin_amdgcn_mfma_f32_16x16x32_bf16(ka1, qb1, a, 0, 0, 0);
            st[sub] = a;
        }

        // ---- no-max softmax: lane owns row q0+wid*16+lan16; keys = j0 + sub*16+quad*4+reg
        {
            const int wbase = 63 - (wid * 16 + lan16) + j0 + quad * 4;
            float ps = 0.f;
            #pragma unroll
            for (int sub = 0; sub < 4; sub++) {
                float e0 = fexp2(st[sub][0] * scale2 + tbl[wbase + sub * 16 + 0]);
                float e1 = fexp2(st[sub][1] * scale2 + tbl[wbase + sub * 16 + 1]);
                float e2 = fexp2(st[sub][2] * scale2 + tbl[wbase + sub * 16 + 2]);
                float e3 = fexp2(st[sub][3] * scale2 + tbl[wbase + sub * 16 + 3]);
                ps += (e0 + e1) + (e2 + e3);
                Pp[wid][lan16][sub * 8 + quad * 2]     = cvtpk_bf16(e0, e1);
                Pp[wid][lan16][sub * 8 + quad * 2 + 1] = cvtpk_bf16(e2, e3);
            }
            l_run += ps;
        }
        asm volatile("s_waitcnt lgkmcnt(0)" ::: "memory");  // wave-private Pp, no barrier

        // ---- O^T += V^T.P^T : V^T A-frags direct from global (L2)
        #pragma unroll
        for (int ks = 0; ks < 2; ks++) {
            short8_t pb = *(const short8_t*)&Pp[wid][lan16][ks * 16 + quad * 4];
            #pragma unroll
            for (int ds = 0; ds < 4; ds++) {
                short8_t va = *(const short8_t*)(vth + (size_t)(ds * 16 + lan16) * SEQ
                                                 + j0 + ks * 32 + quad * 8);
                o[ds] = __builtin_amdgcn_mfma_f32_16x16x32_bf16(va, pb, o[ds], 0, 0, 0);
            }
        }
    }

    // epilogue: reduce l across quads; O^T col=lan16=qrow, row=quad*4+reg=dim; bf16 ctx
    {
        float l = l_run;
        l += __shfl_xor(l, 16);
        l += __shfl_xor(l, 32);
        float inv = 1.0f / l;
        const int n = nh >> 3;
        int row = q0 + wid * 16 + lan16;
        size_t base = ((size_t)n * SEQ + row) * DM + h * DH;
        #pragma unroll
        for (int ds = 0; ds < 4; ds++) {
            uint2 p;
            p.x = cvtpk_bf16(o[ds][0] * inv, o[ds][1] * inv);
            p.y = cvtpk_bf16(o[ds][2] * inv, o[ds][3] * inv);
            *(uint2*)(ctx + base + ds * 16 + quad * 4) = p;
        }
    }
}

extern "C" void kernel_launch(void* const* d_in, const int* in_sizes, int n_in,
                              void* d_out, int out_size, void* d_ws, size_t ws_size,
                              hipStream_t stream) {
    const float* query = (const float*)d_in[0];
    const float* Wq  = (const float*)d_in[1];
    const float* bq  = (const float*)d_in[2];
    const float* Wk  = (const float*)d_in[3];
    const float* bk  = (const float*)d_in[4];
    const float* Wv  = (const float*)d_in[5];
    const float* bv  = (const float*)d_in[6];
    const float* Wp  = (const float*)d_in[7];
    const float* bp  = (const float*)d_in[8];
    const float* lsc = (const float*)d_in[9];
    const float* rpe = (const float*)d_in[10];

    const size_t QEL = (size_t)N_B * SEQ * DM;     // 4,194,304
    const size_t WEL = (size_t)DM * DM;            // 262,144
    char* ws = (char*)d_ws;
    ushort_t* q16  = (ushort_t*)(ws);              // bf16 query
    ushort_t* w16  = q16 + QEL;                    // Wq|Wk|Wv|Wp bf16
    float*    bcat = (float*)(w16 + 4 * WEL);      // 2048 floats
    ushort_t* qb   = (ushort_t*)(bcat + 2048);
    ushort_t* kb   = qb + QEL;
    ushort_t* vtb  = kb + QEL;
    ushort_t* ctx  = vtb + QEL;                    // total ~44 MB (proven footprint)

    prep<<<(Q4 + 4 * W4 + 512 + 255) / 256, 256, 0, stream>>>(
        query, Wq, Wk, Wv, Wp, bq, bk, bv, bp, q16, w16, bcat);

    dim3 g1(1536 / 128, (N_B * SEQ) / 128);        // (12, 64)
    mgemm<0><<<g1, 256, 0, stream>>>(q16, w16, bcat, qb, kb, vtb, nullptr);

    dim3 ga(SEQ / 64, N_B * H_N);                  // (32, 32) = 1024 blocks
    attn_k<<<ga, 256, 0, stream>>>(qb, kb, vtb, lsc, rpe, ctx);

    dim3 g2(DM / 128, (N_B * SEQ) / 128);          // (4, 64)
    mgemm<1><<<g2, 256, 0, stream>>>(ctx, w16 + 3 * WEL, bcat + 1536,
                                     nullptr, nullptr, nullptr, (float*)d_out);
}

// Round 15
// 224.640 us; speedup vs baseline: 1.7076x; 1.7076x over previous
//
#include <hip/hip_runtime.h>
#include <math.h>

#define N_B 4
#define SEQ 2048
#define DM  512
#define H_N 8
#define DH  64

typedef unsigned short ushort_t;
typedef __attribute__((ext_vector_type(8))) short short8_t;
typedef __attribute__((ext_vector_type(4))) float float4_t;

#define LOG2E 1.4426950408889634074f

__device__ __forceinline__ ushort_t f2bf(float f) {
    unsigned int x = __float_as_uint(f);
    unsigned int lsb = (x >> 16) & 1u;
    x += 0x7fffu + lsb;
    return (ushort_t)(x >> 16);
}
__device__ __forceinline__ unsigned int cvtpk_bf16(float a, float b) {
    unsigned int r;
    asm("v_cvt_pk_bf16_f32 %0, %1, %2" : "=v"(r) : "v"(a), "v"(b));
    return r;   // lo = bf16(a), hi = bf16(b), RNE
}
__device__ __forceinline__ float fexp2(float x) {
#if __has_builtin(__builtin_amdgcn_exp2f)
    return __builtin_amdgcn_exp2f(x);
#else
    return exp2f(x);
#endif
}
__device__ __forceinline__ void gload_lds16(const ushort_t* g, ushort_t* l) {
    __builtin_amdgcn_global_load_lds((const __attribute__((address_space(1))) void*)g,
                                     (__attribute__((address_space(3))) void*)l,
                                     16, 0, 0);
}

// Merged pre-pass: query + 4 weights -> bf16 (RNE); bias concat.
#define Q4 1048576   // query float4 groups
#define W4 65536     // per-weight float4 groups
__global__ __launch_bounds__(256)
void prep(const float* __restrict__ query,
          const float* __restrict__ Wq, const float* __restrict__ Wk,
          const float* __restrict__ Wv, const float* __restrict__ Wp,
          const float* __restrict__ bq, const float* __restrict__ bk,
          const float* __restrict__ bv, const float* __restrict__ bp,
          ushort_t* __restrict__ q16, ushort_t* __restrict__ w16,
          float* __restrict__ bcat)
{
    int i = blockIdx.x * 256 + threadIdx.x;
    if (i < Q4) {
        float4 x = ((const float4*)query)[i];
        uint2 p;
        p.x = cvtpk_bf16(x.x, x.y);
        p.y = cvtpk_bf16(x.z, x.w);
        ((uint2*)q16)[i] = p;
    } else if (i < Q4 + 4 * W4) {
        int wi = i - Q4;
        int w = wi >> 16;
        const float* W = (w == 0) ? Wq : (w == 1) ? Wk : (w == 2) ? Wv : Wp;
        float4 x = ((const float4*)W)[wi & (W4 - 1)];
        uint2 p;
        p.x = cvtpk_bf16(x.x, x.y);
        p.y = cvtpk_bf16(x.z, x.w);
        ((uint2*)w16)[wi] = p;
    } else {
        int bi = i - (Q4 + 4 * W4);
        if (bi < 512) {
            int seg = bi >> 7;
            int off = bi & 127;
            const float* B = (seg == 0) ? bq : (seg == 1) ? bk : (seg == 2) ? bv : bp;
            ((float4*)bcat)[bi] = ((const float4*)B)[off];
        }
    }
}

// Single-pass bf16 MFMA GEMM, m97-style: global_load_lds width-16 staging, BK=64,
// unpadded LDS with XOR-8 chunk swizzle folded into the per-lane GLOBAL read offset
// (wave-uniform LDS base requirement). Explicit vmcnt(0) drain before the staging
// barrier: the async DMA's LDS writes are NOT guaranteed to be drained by
// __syncthreads() alone (replay-only race observed in round 14).
// C[m,c] = sum_k A[m,k]*W[c,k] + bias[c]
// MODE 0: B rows 0..1535 (Wq|Wk|Wv): scatter bf16 to q/k (split-head) and vt (transposed).
// MODE 1: fp32 out [m][512].
template<int MODE>
__global__ __launch_bounds__(256)
void mgemm(const ushort_t* __restrict__ A, const ushort_t* __restrict__ B,
           const float* __restrict__ bias,
           ushort_t* __restrict__ q_o, ushort_t* __restrict__ k_o,
           ushort_t* __restrict__ vt_o, float* __restrict__ p_o)
{
    __shared__ __align__(16) ushort_t As[128][64];   // 16 KB, unpadded (row = 128 B)
    __shared__ __align__(16) ushort_t Bs[128][64];

    const int t     = threadIdx.x;
    const int wid   = t >> 6;
    const int lane  = t & 63;
    const int lan16 = lane & 15;
    const int quad  = lane >> 4;
    const int wm    = (wid & 1) * 64;
    const int wn    = (wid >> 1) * 64;

    const int col0 = blockIdx.x * 128;
    const int row0 = blockIdx.y * 128;

    // staging: lane l covers row (l>>3), global chunk (l&7)^((l>>3)&7)  (XOR-8 swizzle)
    const int srow = lane >> 3;                       // 0..7
    const int gchk = (lane & 7) ^ ((lane >> 3) & 7);  // swizzled 16B chunk index
    const ushort_t* gA = A + (size_t)(row0 + wid * 8 + srow) * DM + gchk * 8;
    const ushort_t* gB = B + (size_t)(col0 + wid * 8 + srow) * DM + gchk * 8;

    float4_t acc[4][4];
    #pragma unroll
    for (int i = 0; i < 4; i++)
        #pragma unroll
        for (int j = 0; j < 4; j++) acc[i][j] = (float4_t){0.f, 0.f, 0.f, 0.f};

    const int sw = lan16 & 7;   // fragment-read swizzle key

    for (int k0 = 0; k0 < DM; k0 += 64) {
        __syncthreads();   // prev-iter fragment readers done
        #pragma unroll
        for (int j = 0; j < 4; j++) {
            gload_lds16(gA + k0 + (size_t)j * 32 * DM, &As[j * 32 + wid * 8][0]);
            gload_lds16(gB + k0 + (size_t)j * 32 * DM, &Bs[j * 32 + wid * 8][0]);
        }
        asm volatile("s_waitcnt vmcnt(0)" ::: "memory");  // drain async DMA before barrier
        __syncthreads();   // staging complete

        #pragma unroll
        for (int kk = 0; kk < 2; kk++) {
            short8_t af[4], bf[4];
            #pragma unroll
            for (int i = 0; i < 4; i++) {
                af[i] = *(const short8_t*)&As[wm + i * 16 + lan16][((kk * 4 + quad) ^ sw) * 8];
                bf[i] = *(const short8_t*)&Bs[wn + i * 16 + lan16][((kk * 4 + quad) ^ sw) * 8];
            }
            #pragma unroll
            for (int i = 0; i < 4; i++)
                #pragma unroll
                for (int j = 0; j < 4; j++)
                    acc[i][j] = __builtin_amdgcn_mfma_f32_16x16x32_bf16(af[i], bf[j], acc[i][j], 0, 0, 0);
        }
    }

    #pragma unroll
    for (int j = 0; j < 4; j++) {
        int col = col0 + wn + j * 16 + lan16;
        float bv = bias[col];
        #pragma unroll
        for (int i = 0; i < 4; i++) {
            #pragma unroll
            for (int reg = 0; reg < 4; reg++) {
                int row = row0 + wm + i * 16 + quad * 4 + reg;
                float v = acc[i][j][reg] + bv;
                if (MODE == 0) {
                    int w = col >> 9;
                    int c = col & 511;
                    int hh = c & 7, dh = c >> 3;
                    int n = row >> 11, s = row & 2047;
                    if (w == 0)
                        q_o[(((size_t)(n * H_N + hh)) * SEQ + s) * DH + dh] = f2bf(v);
                    else if (w == 1)
                        k_o[(((size_t)(n * H_N + hh)) * SEQ + s) * DH + dh] = f2bf(v);
                    else
                        vt_o[(((size_t)(n * H_N + hh)) * DH + dh) * SEQ + s] = f2bf(v);
                } else {
                    p_o[(size_t)row * DM + col] = v;
                }
            }
        }
    }
}

// MFMA flash attention (round-10 proven version): S^T orientation, no-max softmax.
// Block = (n, h, 128 q-rows); 4 waves, wave owns 32 q-rows (2 B-frags of 16).
// S^T = K.Q^T  (C: col=lan16=qrow, row=quad*4+reg=key)
// O^T = V^T.P^T (C: col=lan16=qrow, row=quad*4+reg=dim)
__global__ __launch_bounds__(256)
void attn_k(const ushort_t* __restrict__ qw, const ushort_t* __restrict__ kw,
            const ushort_t* __restrict__ vt, const float* __restrict__ lsc,
            const float* __restrict__ rpe, ushort_t* __restrict__ ctx)
{
    __shared__ __align__(16) ushort_t K_s[64][72];          // [key][dim]
    __shared__ __align__(16) ushort_t VT_s[64][72];         // [dim][key]
    __shared__ __align__(16) unsigned int Pp[4][2][16][36]; // [wave][qf][qrow16][key-pair]
    __shared__ float tbl[2176];                             // sigmoid(rpe)*log2e, reversed

    const int t     = threadIdx.x;
    const int wid   = t >> 6;
    const int lane  = t & 63;
    const int lan16 = lane & 15;
    const int quad  = lane >> 4;

    const int qt = blockIdx.x;    // 0..15
    const int h  = blockIdx.y;
    const int n  = blockIdx.z;
    const int q0 = qt * 128;

    const size_t headoff = ((size_t)(n * H_N + h)) * SEQ * DH;
    const ushort_t* qh  = qw + headoff;
    const ushort_t* kh  = kw + headoff;
    const ushort_t* vth = vt + headoff;

    float ls = lsc[h];
    const float lm = 4.60517018598809136804f;   // log(100)
    if (ls > lm) ls = lm;
    const float scale2 = __expf(ls) * 0.04419417382415921757f * LOG2E;

    // tbl[w] = log2e*sigmoid(rpe[q0 + 2174 - w]), reversed so lane reads ascend with key.
    for (int w = t; w < 2175; w += 256) {
        int v = q0 + 2174 - w;
        float x = rpe[v * H_N + h];
        tbl[w] = LOG2E / (1.0f + __expf(-x));
    }

    // Q as B-operand: lane lan16 = qrow, holds d = half*32+quad*8..+7
    short8_t qb[2][2];
    #pragma unroll
    for (int qf = 0; qf < 2; qf++) {
        const ushort_t* src = qh + (size_t)(q0 + wid * 32 + qf * 16 + lan16) * DH + quad * 8;
        qb[qf][0] = *(const short8_t*)(src);
        qb[qf][1] = *(const short8_t*)(src + 32);
    }

    float l_run[2] = {0.f, 0.f};
    float4_t o[4][2];   // [dim-sub][qf]
    #pragma unroll
    for (int ds = 0; ds < 4; ds++)
        #pragma unroll
        for (int qf = 0; qf < 2; qf++) o[ds][qf] = (float4_t){0.f, 0.f, 0.f, 0.f};

    const int key_st = t >> 2;
    const int part   = t & 3;

    for (int j0 = 0; j0 < SEQ; j0 += 64) {
        __syncthreads();   // prev-tile readers done (also covers tbl build on first pass)
        {
            const ushort_t* ksrc = kh + (size_t)(j0 + key_st) * DH + part * 16;
            *(uint4*)&K_s[key_st][part * 16]     = *(const uint4*)(ksrc);
            *(uint4*)&K_s[key_st][part * 16 + 8] = *(const uint4*)(ksrc + 8);
            const ushort_t* vsrc = vth + (size_t)key_st * SEQ + j0 + part * 16;
            *(uint4*)&VT_s[key_st][part * 16]     = *(const uint4*)(vsrc);
            *(uint4*)&VT_s[key_st][part * 16 + 8] = *(const uint4*)(vsrc + 8);
        }
        __syncthreads();

        // ---- S^T = K.Q^T : per wave [64 keys x 32 qrows]
        float4_t st[4][2];
        #pragma unroll
        for (int sub = 0; sub < 4; sub++) {
            const ushort_t* kp = &K_s[sub * 16 + lan16][quad * 8];
            short8_t ka0 = *(const short8_t*)(kp);
            short8_t ka1 = *(const short8_t*)(kp + 32);
            #pragma unroll
            for (int qf = 0; qf < 2; qf++) {
                float4_t a = (float4_t){0.f, 0.f, 0.f, 0.f};
                a = __builtin_amdgcn_mfma_f32_16x16x32_bf16(ka0, qb[qf][0], a, 0, 0, 0);
                a = __builtin_amdgcn_mfma_f32_16x16x32_bf16(ka1, qb[qf][1], a, 0, 0, 0);
                st[sub][qf] = a;
            }
        }

        // ---- no-max softmax: lane owns row q0+wid*32+qf*16+lan16; keys sub*16+quad*4+reg
        #pragma unroll
        for (int qf = 0; qf < 2; qf++) {
            const int wbase = 127 - (wid * 32 + qf * 16 + lan16) + j0 + quad * 4;
            float ps = 0.f;
            #pragma unroll
            for (int sub = 0; sub < 4; sub++) {
                float e0 = fexp2(st[sub][qf][0] * scale2 + tbl[wbase + sub * 16 + 0]);
                float e1 = fexp2(st[sub][qf][1] * scale2 + tbl[wbase + sub * 16 + 1]);
                float e2 = fexp2(st[sub][qf][2] * scale2 + tbl[wbase + sub * 16 + 2]);
                float e3 = fexp2(st[sub][qf][3] * scale2 + tbl[wbase + sub * 16 + 3]);
                ps += (e0 + e1) + (e2 + e3);
                Pp[wid][qf][lan16][sub * 8 + quad * 2]     = cvtpk_bf16(e0, e1);
                Pp[wid][qf][lan16][sub * 8 + quad * 2 + 1] = cvtpk_bf16(e2, e3);
            }
            l_run[qf] += ps;
        }
        asm volatile("s_waitcnt lgkmcnt(0)" ::: "memory");  // wave-private Pp, no barrier

        // ---- O^T += V^T.P^T
        #pragma unroll
        for (int ks = 0; ks < 2; ks++) {
            short8_t pb[2];
            #pragma unroll
            for (int qf = 0; qf < 2; qf++)
                pb[qf] = *(const short8_t*)&Pp[wid][qf][lan16][ks * 16 + quad * 4];
            #pragma unroll
            for (int ds = 0; ds < 4; ds++) {
                short8_t va = *(const short8_t*)&VT_s[ds * 16 + lan16][ks * 32 + quad * 8];
                #pragma unroll
                for (int qf = 0; qf < 2; qf++)
                    o[ds][qf] = __builtin_amdgcn_mfma_f32_16x16x32_bf16(va, pb[qf], o[ds][qf], 0, 0, 0);
            }
        }
    }

    // epilogue: reduce l across quads; O^T col=lan16=qrow, row=quad*4+reg=dim; bf16 ctx
    #pragma unroll
    for (int qf = 0; qf < 2; qf++) {
        float l = l_run[qf];
        l += __shfl_xor(l, 16);
        l += __shfl_xor(l, 32);
        float inv = 1.0f / l;
        int row = q0 + wid * 32 + qf * 16 + lan16;
        size_t base = ((size_t)n * SEQ + row) * DM + h * DH;
        #pragma unroll
        for (int ds = 0; ds < 4; ds++) {
            uint2 p;
            p.x = cvtpk_bf16(o[ds][qf][0] * inv, o[ds][qf][1] * inv);
            p.y = cvtpk_bf16(o[ds][qf][2] * inv, o[ds][qf][3] * inv);
            *(uint2*)(ctx + base + ds * 16 + quad * 4) = p;
        }
    }
}

extern "C" void kernel_launch(void* const* d_in, const int* in_sizes, int n_in,
                              void* d_out, int out_size, void* d_ws, size_t ws_size,
                              hipStream_t stream) {
    const float* query = (const float*)d_in[0];
    const float* Wq  = (const float*)d_in[1];
    const float* bq  = (const float*)d_in[2];
    const float* Wk  = (const float*)d_in[3];
    const float* bk  = (const float*)d_in[4];
    const float* Wv  = (const float*)d_in[5];
    const float* bv  = (const float*)d_in[6];
    const float* Wp  = (const float*)d_in[7];
    const float* bp  = (const float*)d_in[8];
    const float* lsc = (const float*)d_in[9];
    const float* rpe = (const float*)d_in[10];

    const size_t QEL = (size_t)N_B * SEQ * DM;     // 4,194,304
    const size_t WEL = (size_t)DM * DM;            // 262,144
    char* ws = (char*)d_ws;
    ushort_t* q16  = (ushort_t*)(ws);              // bf16 query
    ushort_t* w16  = q16 + QEL;                    // Wq|Wk|Wv|Wp bf16
    float*    bcat = (float*)(w16 + 4 * WEL);      // 2048 floats
    ushort_t* qb   = (ushort_t*)(bcat + 2048);
    ushort_t* kb   = qb + QEL;
    ushort_t* vtb  = kb + QEL;
    ushort_t* ctx  = vtb + QEL;                    // total ~44 MB (proven footprint)

    prep<<<(Q4 + 4 * W4 + 512 + 255) / 256, 256, 0, stream>>>(
        query, Wq, Wk, Wv, Wp, bq, bk, bv, bp, q16, w16, bcat);

    dim3 g1(1536 / 128, (N_B * SEQ) / 128);        // (12, 64)
    mgemm<0><<<g1, 256, 0, stream>>>(q16, w16, bcat, qb, kb, vtb, nullptr);

    dim3 ga(SEQ / 128, H_N, N_B);                  // (16, 8, 4)
    attn_k<<<ga, 256, 0, stream>>>(qb, kb, vtb, lsc, rpe, ctx);

    dim3 g2(DM / 128, (N_B * SEQ) / 128);          // (4, 64)
    mgemm<1><<<g2, 256, 0, stream>>>(ctx, w16 + 3 * WEL, bcat + 1536,
                                     nullptr, nullptr, nullptr, (float*)d_out);
}